// Round 2
// baseline (3381.614 us; speedup 1.0000x reference)
//
#include <hip/hip_runtime.h>

// ---------------------------------------------------------------------------
// Threefry2x32 (JAX-compatible) + erfinv (XLA f32 polynomial)
// ---------------------------------------------------------------------------
#define TF_ROUND(r) { x0 += x1; x1 = ((x1<<(r))|(x1>>(32-(r)))); x1 ^= x0; }

__device__ __forceinline__ void tf2x32(unsigned k0, unsigned k1, unsigned x0, unsigned x1,
                                       unsigned &o0, unsigned &o1)
{
  unsigned ks2 = k0 ^ k1 ^ 0x1BD11BDAu;
  x0 += k0; x1 += k1;
  TF_ROUND(13) TF_ROUND(15) TF_ROUND(26) TF_ROUND(6)
  x0 += k1;  x1 += ks2 + 1u;
  TF_ROUND(17) TF_ROUND(29) TF_ROUND(16) TF_ROUND(24)
  x0 += ks2; x1 += k0 + 2u;
  TF_ROUND(13) TF_ROUND(15) TF_ROUND(26) TF_ROUND(6)
  x0 += k0;  x1 += k1 + 3u;
  TF_ROUND(17) TF_ROUND(29) TF_ROUND(16) TF_ROUND(24)
  x0 += k1;  x1 += ks2 + 4u;
  TF_ROUND(13) TF_ROUND(15) TF_ROUND(26) TF_ROUND(6)
  x0 += ks2; x1 += k0 + 5u;
  o0 = x0; o1 = x1;
}

__device__ __forceinline__ float erfinv_f(float x)
{
  float w = -log1pf(-x * x);
  float p;
  if (w < 5.0f) {
    w -= 2.5f;
    p = 2.81022636e-08f;
    p = fmaf(p, w, 3.43273939e-07f);
    p = fmaf(p, w, -3.5233877e-06f);
    p = fmaf(p, w, -4.39150654e-06f);
    p = fmaf(p, w, 0.00021858087f);
    p = fmaf(p, w, -0.00125372503f);
    p = fmaf(p, w, -0.00417768164f);
    p = fmaf(p, w, 0.246640727f);
    p = fmaf(p, w, 1.50140941f);
  } else {
    w = sqrtf(w) - 3.0f;
    p = -0.000200214257f;
    p = fmaf(p, w, 0.000100950558f);
    p = fmaf(p, w, 0.00134934322f);
    p = fmaf(p, w, -0.00367342844f);
    p = fmaf(p, w, 0.00573950773f);
    p = fmaf(p, w, -0.0076224613f);
    p = fmaf(p, w, 0.00943887047f);
    p = fmaf(p, w, 1.00167406f);
    p = fmaf(p, w, 2.83297682f);
  }
  return p * x;
}

__device__ __forceinline__ float rng_normal(unsigned b)
{
  // jax.random.normal: u = uniform(lo=nextafter(-1,0), hi=1); sqrt(2)*erfinv(u)
  float f = __uint_as_float((b >> 9) | 0x3f800000u) - 1.0f;  // [0,1)
  const float lo = -0.99999994f;
  float u = fmaxf(lo, f * 2.0f + lo);   // (hi - lo) rounds to exactly 2.0f
  return 1.41421356f * erfinv_f(u);
}

__device__ __forceinline__ float softplusf(float x) { return log1pf(expf(x)); }

// ---------------------------------------------------------------------------
// DDE (PEConv mean) kernels
// ---------------------------------------------------------------------------
__global__ void dde_count(const int* __restrict__ h, const int* __restrict__ t,
                          float* __restrict__ cnt_t, float* __restrict__ cnt_h, int E)
{
  int e = blockIdx.x * blockDim.x + threadIdx.x;
  if (e >= E) return;
  atomicAdd(&cnt_t[t[e]], 1.0f);
  atomicAdd(&cnt_h[h[e]], 1.0f);
}

__global__ void dde_scatter1(const int* __restrict__ h, const int* __restrict__ t,
                             const float* __restrict__ topic,
                             float* __restrict__ f1, float* __restrict__ g1, int E)
{
  int e = blockIdx.x * blockDim.x + threadIdx.x;
  if (e >= E) return;
  int hh = h[e], tt = t[e];
  atomicAdd(&f1[tt*2+0], topic[hh*2+0]);
  atomicAdd(&f1[tt*2+1], topic[hh*2+1]);
  atomicAdd(&g1[hh*2+0], topic[tt*2+0]);
  atomicAdd(&g1[hh*2+1], topic[tt*2+1]);
}

__global__ void dde_scatter2(const int* __restrict__ h, const int* __restrict__ t,
                             const float* __restrict__ f1, const float* __restrict__ g1,
                             float* __restrict__ f2, float* __restrict__ g2, int E)
{
  int e = blockIdx.x * blockDim.x + threadIdx.x;
  if (e >= E) return;
  int hh = h[e], tt = t[e];
  atomicAdd(&f2[tt*2+0], f1[hh*2+0]);
  atomicAdd(&f2[tt*2+1], f1[hh*2+1]);
  atomicAdd(&g2[hh*2+0], g1[tt*2+0]);
  atomicAdd(&g2[hh*2+1], g1[tt*2+1]);
}

__global__ void dde_norm(float* __restrict__ f, float* __restrict__ g,
                         const float* __restrict__ ct, const float* __restrict__ ch, int N)
{
  int n = blockIdx.x * blockDim.x + threadIdx.x;
  if (n >= N) return;
  float dt = fmaxf(ct[n], 1.0f);
  float dh = fmaxf(ch[n], 1.0f);
  f[n*2+0] /= dt; f[n*2+1] /= dt;
  g[n*2+0] /= dh; g[n*2+1] /= dh;
}

// ---------------------------------------------------------------------------
// Entity feature matrix h_e : [N][288] (266 real cols + zero pad)
// cols 0..255 emb, 256..257 topic, 258..259 f1, 260..261 f2, 262..263 g1, 264..265 g2
// ---------------------------------------------------------------------------
__global__ void build_he(const float* __restrict__ emb, const float* __restrict__ nte,
                         const float* __restrict__ topic,
                         const float* __restrict__ f1, const float* __restrict__ f2,
                         const float* __restrict__ g1, const float* __restrict__ g2,
                         float* __restrict__ He, int N, int nText)
{
  int idx = blockIdx.x * blockDim.x + threadIdx.x;
  if (idx >= N * 288) return;
  int n = idx / 288, j = idx - n * 288;
  float v;
  if (j < 256)      v = (n < nText) ? emb[(size_t)n*256 + j] : nte[j];
  else if (j < 258) v = topic[n*2 + (j-256)];
  else if (j < 260) v = f1[n*2 + (j-258)];
  else if (j < 262) v = f2[n*2 + (j-260)];
  else if (j < 264) v = g1[n*2 + (j-262)];
  else if (j < 266) v = g2[n*2 + (j-264)];
  else              v = 0.0f;
  He[idx] = v;
}

// ---------------------------------------------------------------------------
// Bayesian weight sampling — JAX threefry, PARTITIONABLE semantics (jax>=0.4.36
// default): random_bits(shape) uses one threefry call PER ELEMENT with counter
// (hi32(i), lo32(i)) and bits = o0 ^ o1; split(k,4) gives sk_j = tf(k, 0, j)
// (both output words). fold_in(key(42), s) = tf((0,42), 0, s) (both words).
//   sk0->w1(256x1044), sk1->b1(256), sk2->w2(256), sk3->b2(1)
// ---------------------------------------------------------------------------
__global__ void sample_kernel(int s,
                              const float* __restrict__ w1_mu, const float* __restrict__ w1_rho,
                              const float* __restrict__ b1_mu, const float* __restrict__ b1_rho,
                              const float* __restrict__ w2_mu, const float* __restrict__ w2_rho,
                              const float* __restrict__ b2_mu, const float* __restrict__ b2_rho,
                              float* __restrict__ W1s, float* __restrict__ b1s,
                              float* __restrict__ w2s, float* __restrict__ b2s)
{
  const int W1N = 267264;   // 256*1044
  int tid = blockIdx.x * blockDim.x + threadIdx.x;
  unsigned F0, F1;
  tf2x32(0u, 42u, 0u, (unsigned)s, F0, F1);   // fold_in(key(42), s)

  if (tid < W1N) {
    unsigned k0, k1; tf2x32(F0, F1, 0u, 0u, k0, k1);              // sk0
    unsigned o0, o1; tf2x32(k0, k1, 0u, (unsigned)tid, o0, o1);
    W1s[tid] = fmaf(rng_normal(o0 ^ o1), softplusf(w1_rho[tid]), w1_mu[tid]);
  } else if (tid < W1N + 256) {
    int m = tid - W1N;
    unsigned k0, k1; tf2x32(F0, F1, 0u, 1u, k0, k1);              // sk1
    unsigned o0, o1; tf2x32(k0, k1, 0u, (unsigned)m, o0, o1);
    b1s[m] = fmaf(rng_normal(o0 ^ o1), softplusf(b1_rho[m]), b1_mu[m]);
  } else if (tid < W1N + 512) {
    int m = tid - (W1N + 256);
    unsigned k0, k1; tf2x32(F0, F1, 0u, 2u, k0, k1);              // sk2
    unsigned o0, o1; tf2x32(k0, k1, 0u, (unsigned)m, o0, o1);
    w2s[m] = fmaf(rng_normal(o0 ^ o1), softplusf(w2_rho[m]), w2_mu[m]);
  } else if (tid == W1N + 512) {
    unsigned k0, k1; tf2x32(F0, F1, 0u, 3u, k0, k1);              // sk3
    unsigned o0, o1; tf2x32(k0, k1, 0u, 0u, o0, o1);
    b2s[0] = fmaf(rng_normal(o0 ^ o1), softplusf(b2_rho[0]), b2_mu[0]);
  }
}

// Pack A = [W1[:,256:522]; W1[:,778:1044]]  ->  As[512][288] (zero-padded K)
__global__ void pack_kernel(const float* __restrict__ W1s, float* __restrict__ As)
{
  int idx = blockIdx.x * blockDim.x + threadIdx.x;
  if (idx >= 512 * 288) return;
  int m = idx / 288, j = idx - m * 288;
  float v = 0.0f;
  if (j < 266) v = (m < 256) ? W1s[m*1044 + 256 + j] : W1s[(m-256)*1044 + 778 + j];
  As[idx] = v;
}

// c[k] = b1s[k] + sum_j W1s[k][j] * q[j]   (q slice, cols 0..255)
__global__ void c_kernel(const float* __restrict__ W1s, const float* __restrict__ b1s,
                         const float* __restrict__ q, float* __restrict__ cvec)
{
  int k = threadIdx.x;
  float acc = b1s[k];
  for (int j = 0; j < 256; ++j) acc = fmaf(W1s[k*1044 + j], q[j], acc);
  cvec[k] = acc;
}

// Ar[r][k] = sum_j W1s[k][522+j] * rel[r][j]
__global__ void ar_kernel(const float* __restrict__ W1s, const float* __restrict__ rel,
                          float* __restrict__ Ar)
{
  __shared__ float rsh[256];
  int r = blockIdx.x, k = threadIdx.x;
  rsh[k] = rel[(size_t)r*256 + k];
  __syncthreads();
  float acc = 0.0f;
  for (int j = 0; j < 256; ++j) acc = fmaf(W1s[k*1044 + 522 + j], rsh[j], acc);
  Ar[(size_t)r*256 + k] = acc;
}

// ---------------------------------------------------------------------------
// GEMM: U[n][m] = sum_k As[m][k] * He[n][k]   M=512, K=288, N=nEnt
// 64x64 tile, 256 threads, 4x4 per thread, KC=32
// ---------------------------------------------------------------------------
#define KC 32
__global__ __launch_bounds__(256) void gemm_kernel(const float* __restrict__ As,
                                                   const float* __restrict__ He,
                                                   float* __restrict__ U, int nEnt)
{
  __shared__ float sA[KC][68];
  __shared__ float sB[KC][68];
  const int tid = threadIdx.x;
  const int n0 = blockIdx.x * 64;
  const int m0 = blockIdx.y * 64;
  const int tx = tid & 15, ty = tid >> 4;
  const int lr = tid >> 2;          // 0..63
  const int lk = (tid & 3) * 8;     // 0,8,16,24
  float acc[4][4] = {};

  for (int k0 = 0; k0 < 288; k0 += KC) {
    const float4* pa = reinterpret_cast<const float4*>(&As[(size_t)(m0 + lr) * 288 + k0 + lk]);
    float4 a0 = pa[0], a1 = pa[1];
    float4 b0 = make_float4(0,0,0,0), b1v = make_float4(0,0,0,0);
    int n = n0 + lr;
    if (n < nEnt) {
      const float4* pb = reinterpret_cast<const float4*>(&He[(size_t)n * 288 + k0 + lk]);
      b0 = pb[0]; b1v = pb[1];
    }
    __syncthreads();
    sA[lk+0][lr]=a0.x; sA[lk+1][lr]=a0.y; sA[lk+2][lr]=a0.z; sA[lk+3][lr]=a0.w;
    sA[lk+4][lr]=a1.x; sA[lk+5][lr]=a1.y; sA[lk+6][lr]=a1.z; sA[lk+7][lr]=a1.w;
    sB[lk+0][lr]=b0.x; sB[lk+1][lr]=b0.y; sB[lk+2][lr]=b0.z; sB[lk+3][lr]=b0.w;
    sB[lk+4][lr]=b1v.x; sB[lk+5][lr]=b1v.y; sB[lk+6][lr]=b1v.z; sB[lk+7][lr]=b1v.w;
    __syncthreads();
    #pragma unroll
    for (int kk = 0; kk < KC; ++kk) {
      const float4 av = *reinterpret_cast<const float4*>(&sA[kk][ty*4]);
      const float4 bv = *reinterpret_cast<const float4*>(&sB[kk][tx*4]);
      const float a[4] = {av.x, av.y, av.z, av.w};
      const float b[4] = {bv.x, bv.y, bv.z, bv.w};
      #pragma unroll
      for (int i = 0; i < 4; ++i)
        #pragma unroll
        for (int j = 0; j < 4; ++j)
          acc[i][j] = fmaf(a[i], b[j], acc[i][j]);
    }
  }
  #pragma unroll
  for (int j = 0; j < 4; ++j) {
    int n = n0 + tx*4 + j;
    if (n < nEnt) {
      float4 v = make_float4(acc[0][j], acc[1][j], acc[2][j], acc[3][j]);
      *reinterpret_cast<float4*>(&U[(size_t)n * 512 + m0 + ty*4]) = v;
    }
  }
}

// ---------------------------------------------------------------------------
// Edge pass: one wave per edge. pre[k] = c[k] + U[h][k] + Ar[r][k] + U[t][256+k]
// out contribution = w2 . relu(pre) + b2
// mode 0: store, 1: accumulate, 2: accumulate + *0.2 (mean over 5 samples)
// ---------------------------------------------------------------------------
__global__ __launch_bounds__(256) void edge_kernel(const int* __restrict__ h,
                                                   const int* __restrict__ t,
                                                   const int* __restrict__ r,
                                                   const float* __restrict__ U,
                                                   const float* __restrict__ Ar,
                                                   const float* __restrict__ cvec,
                                                   const float* __restrict__ w2s,
                                                   const float* __restrict__ b2s,
                                                   float* __restrict__ out, int E, int mode)
{
  int gid = blockIdx.x * blockDim.x + threadIdx.x;
  int e = gid >> 6;
  int lane = threadIdx.x & 63;
  if (e >= E) return;
  int hh = h[e], tt = t[e], rr = r[e];
  const float4 uh = *reinterpret_cast<const float4*>(&U[(size_t)hh * 512 + lane*4]);
  const float4 ut = *reinterpret_cast<const float4*>(&U[(size_t)tt * 512 + 256 + lane*4]);
  const float4 ar = *reinterpret_cast<const float4*>(&Ar[(size_t)rr * 256 + lane*4]);
  const float4 cc = *reinterpret_cast<const float4*>(&cvec[lane*4]);
  const float4 ww = *reinterpret_cast<const float4*>(&w2s[lane*4]);
  float sum = ww.x * fmaxf(cc.x + uh.x + ar.x + ut.x, 0.0f)
            + ww.y * fmaxf(cc.y + uh.y + ar.y + ut.y, 0.0f)
            + ww.z * fmaxf(cc.z + uh.z + ar.z + ut.z, 0.0f)
            + ww.w * fmaxf(cc.w + uh.w + ar.w + ut.w, 0.0f);
  #pragma unroll
  for (int off = 32; off >= 1; off >>= 1) sum += __shfl_down(sum, off, 64);
  if (lane == 0) {
    float v = sum + b2s[0];
    if (mode == 0)      out[e] = v;
    else if (mode == 1) out[e] += v;
    else                out[e] = (out[e] + v) * 0.2f;
  }
}

// ---------------------------------------------------------------------------
// Host launcher
// ---------------------------------------------------------------------------
extern "C" void kernel_launch(void* const* d_in, const int* in_sizes, int n_in,
                              void* d_out, int out_size, void* d_ws, size_t ws_size,
                              hipStream_t stream)
{
  const int*   h_id  = (const int*)  d_in[0];
  const int*   r_id  = (const int*)  d_in[1];
  const int*   t_id  = (const int*)  d_in[2];
  const float* q     = (const float*)d_in[3];
  const float* emb   = (const float*)d_in[4];
  const float* rel   = (const float*)d_in[6];
  const float* topic = (const float*)d_in[7];
  const float* nte   = (const float*)d_in[8];
  const float* w1_mu = (const float*)d_in[9];
  const float* w1_rho= (const float*)d_in[10];
  const float* b1_mu = (const float*)d_in[11];
  const float* b1_rho= (const float*)d_in[12];
  const float* w2_mu = (const float*)d_in[13];
  const float* w2_rho= (const float*)d_in[14];
  const float* b2_mu = (const float*)d_in[15];
  const float* b2_rho= (const float*)d_in[16];

  const int E     = in_sizes[0];
  const int nText = in_sizes[4] / 256;
  const int N     = in_sizes[7] / 2;
  const int NR    = in_sizes[6] / 256;
  float* out = (float*)d_out;

  char* ws = (char*)d_ws;
  size_t off = 0;
  auto alloc = [&](size_t elems) -> float* {
    float* p = (float*)(ws + off);
    off += ((elems * 4 + 255) / 256) * 256;
    return p;
  };
  float* He   = alloc((size_t)N * 288);
  float* U    = alloc((size_t)N * 512);
  float* W1s  = alloc(256 * 1044);
  float* As   = alloc(512 * 288);
  float* b1s  = alloc(256);
  float* w2s  = alloc(256);
  float* b2s  = alloc(64);
  float* cvec = alloc(256);
  float* Ar   = alloc((size_t)NR * 256);
  float* cnt_t = alloc(N);
  float* cnt_h = alloc(N);
  float* f1 = alloc((size_t)2*N);
  float* f2 = alloc((size_t)2*N);
  float* g1 = alloc((size_t)2*N);
  float* g2 = alloc((size_t)2*N);

  // zero the atomic-accumulated DDE region (cnt_t .. g2, contiguous)
  size_t dde_bytes = (size_t)((char*)(g2 + 2*(size_t)N) - (char*)cnt_t);
  hipMemsetAsync(cnt_t, 0, dde_bytes, stream);

  int eb = (E + 255) / 256;
  int nb = (N + 255) / 256;
  dde_count   <<<eb, 256, 0, stream>>>(h_id, t_id, cnt_t, cnt_h, E);
  dde_scatter1<<<eb, 256, 0, stream>>>(h_id, t_id, topic, f1, g1, E);
  dde_norm    <<<nb, 256, 0, stream>>>(f1, g1, cnt_t, cnt_h, N);
  dde_scatter2<<<eb, 256, 0, stream>>>(h_id, t_id, f1, g1, f2, g2, E);
  dde_norm    <<<nb, 256, 0, stream>>>(f2, g2, cnt_t, cnt_h, N);

  int heb = ((int)((size_t)N * 288) + 255) / 256;
  build_he<<<heb, 256, 0, stream>>>(emb, nte, topic, f1, f2, g1, g2, He, N, nText);

  dim3 ggrid((N + 63) / 64, 8);
  for (int s = 0; s < 5; ++s) {
    sample_kernel<<<(267264 + 513 + 255) / 256, 256, 0, stream>>>(
        s, w1_mu, w1_rho, b1_mu, b1_rho, w2_mu, w2_rho, b2_mu, b2_rho,
        W1s, b1s, w2s, b2s);
    pack_kernel<<<(512*288 + 255)/256, 256, 0, stream>>>(W1s, As);
    c_kernel   <<<1, 256, 0, stream>>>(W1s, b1s, q, cvec);
    ar_kernel  <<<NR, 256, 0, stream>>>(W1s, rel, Ar);
    gemm_kernel<<<ggrid, 256, 0, stream>>>(As, He, U, N);
    int mode = (s == 0) ? 0 : ((s == 4) ? 2 : 1);
    edge_kernel<<<(E + 3) / 4, 256, 0, stream>>>(h_id, t_id, r_id, U, Ar, cvec,
                                                 w2s, b2s, out, E, mode);
  }
  (void)n_in; (void)out_size; (void)ws_size;
}

// Round 3
// 1646.831 us; speedup vs baseline: 2.0534x; 2.0534x over previous
//
#include <hip/hip_runtime.h>
#include <hip/hip_bf16.h>

typedef __attribute__((ext_vector_type(8))) short short8;
typedef __attribute__((ext_vector_type(4))) float f32x4;

// ---------------------------------------------------------------------------
// Threefry2x32 (JAX partitionable semantics) + erfinv (XLA f32 polynomial)
// ---------------------------------------------------------------------------
#define TF_ROUND(r) { x0 += x1; x1 = ((x1<<(r))|(x1>>(32-(r)))); x1 ^= x0; }

__device__ __forceinline__ void tf2x32(unsigned k0, unsigned k1, unsigned x0, unsigned x1,
                                       unsigned &o0, unsigned &o1)
{
  unsigned ks2 = k0 ^ k1 ^ 0x1BD11BDAu;
  x0 += k0; x1 += k1;
  TF_ROUND(13) TF_ROUND(15) TF_ROUND(26) TF_ROUND(6)
  x0 += k1;  x1 += ks2 + 1u;
  TF_ROUND(17) TF_ROUND(29) TF_ROUND(16) TF_ROUND(24)
  x0 += ks2; x1 += k0 + 2u;
  TF_ROUND(13) TF_ROUND(15) TF_ROUND(26) TF_ROUND(6)
  x0 += k0;  x1 += k1 + 3u;
  TF_ROUND(17) TF_ROUND(29) TF_ROUND(16) TF_ROUND(24)
  x0 += k1;  x1 += ks2 + 4u;
  TF_ROUND(13) TF_ROUND(15) TF_ROUND(26) TF_ROUND(6)
  x0 += ks2; x1 += k0 + 5u;
  o0 = x0; o1 = x1;
}

__device__ __forceinline__ float erfinv_f(float x)
{
  float w = -log1pf(-x * x);
  float p;
  if (w < 5.0f) {
    w -= 2.5f;
    p = 2.81022636e-08f;
    p = fmaf(p, w, 3.43273939e-07f);
    p = fmaf(p, w, -3.5233877e-06f);
    p = fmaf(p, w, -4.39150654e-06f);
    p = fmaf(p, w, 0.00021858087f);
    p = fmaf(p, w, -0.00125372503f);
    p = fmaf(p, w, -0.00417768164f);
    p = fmaf(p, w, 0.246640727f);
    p = fmaf(p, w, 1.50140941f);
  } else {
    w = sqrtf(w) - 3.0f;
    p = -0.000200214257f;
    p = fmaf(p, w, 0.000100950558f);
    p = fmaf(p, w, 0.00134934322f);
    p = fmaf(p, w, -0.00367342844f);
    p = fmaf(p, w, 0.00573950773f);
    p = fmaf(p, w, -0.0076224613f);
    p = fmaf(p, w, 0.00943887047f);
    p = fmaf(p, w, 1.00167406f);
    p = fmaf(p, w, 2.83297682f);
  }
  return p * x;
}

__device__ __forceinline__ float rng_normal(unsigned b)
{
  float f = __uint_as_float((b >> 9) | 0x3f800000u) - 1.0f;  // [0,1)
  const float lo = -0.99999994f;
  float u = fmaxf(lo, f * 2.0f + lo);
  return 1.41421356f * erfinv_f(u);
}

__device__ __forceinline__ float softplusf(float x) { return log1pf(expf(x)); }

// ---------------------------------------------------------------------------
// DDE (PEConv mean) kernels
// ---------------------------------------------------------------------------
__global__ void dde_count(const int* __restrict__ h, const int* __restrict__ t,
                          float* __restrict__ cnt_t, float* __restrict__ cnt_h, int E)
{
  int e = blockIdx.x * blockDim.x + threadIdx.x;
  if (e >= E) return;
  atomicAdd(&cnt_t[t[e]], 1.0f);
  atomicAdd(&cnt_h[h[e]], 1.0f);
}

__global__ void dde_scatter1(const int* __restrict__ h, const int* __restrict__ t,
                             const float* __restrict__ topic,
                             float* __restrict__ f1, float* __restrict__ g1, int E)
{
  int e = blockIdx.x * blockDim.x + threadIdx.x;
  if (e >= E) return;
  int hh = h[e], tt = t[e];
  atomicAdd(&f1[tt*2+0], topic[hh*2+0]);
  atomicAdd(&f1[tt*2+1], topic[hh*2+1]);
  atomicAdd(&g1[hh*2+0], topic[tt*2+0]);
  atomicAdd(&g1[hh*2+1], topic[tt*2+1]);
}

__global__ void dde_scatter2(const int* __restrict__ h, const int* __restrict__ t,
                             const float* __restrict__ f1, const float* __restrict__ g1,
                             float* __restrict__ f2, float* __restrict__ g2, int E)
{
  int e = blockIdx.x * blockDim.x + threadIdx.x;
  if (e >= E) return;
  int hh = h[e], tt = t[e];
  atomicAdd(&f2[tt*2+0], f1[hh*2+0]);
  atomicAdd(&f2[tt*2+1], f1[hh*2+1]);
  atomicAdd(&g2[hh*2+0], g1[tt*2+0]);
  atomicAdd(&g2[hh*2+1], g1[tt*2+1]);
}

__global__ void dde_norm(float* __restrict__ f, float* __restrict__ g,
                         const float* __restrict__ ct, const float* __restrict__ ch, int N)
{
  int n = blockIdx.x * blockDim.x + threadIdx.x;
  if (n >= N) return;
  float dt = fmaxf(ct[n], 1.0f);
  float dh = fmaxf(ch[n], 1.0f);
  f[n*2+0] /= dt; f[n*2+1] /= dt;
  g[n*2+0] /= dh; g[n*2+1] /= dh;
}

// ---------------------------------------------------------------------------
// Entity feature matrix h_e : [N][288] bf16 (266 real cols + zero pad)
// ---------------------------------------------------------------------------
__global__ void build_he(const float* __restrict__ emb, const float* __restrict__ nte,
                         const float* __restrict__ topic,
                         const float* __restrict__ f1, const float* __restrict__ f2,
                         const float* __restrict__ g1, const float* __restrict__ g2,
                         __hip_bfloat16* __restrict__ He, int N, int nText)
{
  int idx = blockIdx.x * blockDim.x + threadIdx.x;
  if (idx >= N * 288) return;
  int n = idx / 288, j = idx - n * 288;
  float v;
  if (j < 256)      v = (n < nText) ? emb[(size_t)n*256 + j] : nte[j];
  else if (j < 258) v = topic[n*2 + (j-256)];
  else if (j < 260) v = f1[n*2 + (j-258)];
  else if (j < 262) v = f2[n*2 + (j-260)];
  else if (j < 264) v = g1[n*2 + (j-262)];
  else if (j < 266) v = g2[n*2 + (j-264)];
  else              v = 0.0f;
  He[idx] = __float2bfloat16(v);
}

// ---------------------------------------------------------------------------
// Bayesian weight sampling (JAX threefry, partitionable semantics) — verified
// ---------------------------------------------------------------------------
__global__ void sample_kernel(int s,
                              const float* __restrict__ w1_mu, const float* __restrict__ w1_rho,
                              const float* __restrict__ b1_mu, const float* __restrict__ b1_rho,
                              const float* __restrict__ w2_mu, const float* __restrict__ w2_rho,
                              const float* __restrict__ b2_mu, const float* __restrict__ b2_rho,
                              float* __restrict__ W1s, float* __restrict__ b1s,
                              float* __restrict__ w2s, float* __restrict__ b2s)
{
  const int W1N = 267264;   // 256*1044
  int tid = blockIdx.x * blockDim.x + threadIdx.x;
  unsigned F0, F1;
  tf2x32(0u, 42u, 0u, (unsigned)s, F0, F1);   // fold_in(key(42), s)

  if (tid < W1N) {
    unsigned k0, k1; tf2x32(F0, F1, 0u, 0u, k0, k1);              // sk0
    unsigned o0, o1; tf2x32(k0, k1, 0u, (unsigned)tid, o0, o1);
    W1s[tid] = fmaf(rng_normal(o0 ^ o1), softplusf(w1_rho[tid]), w1_mu[tid]);
  } else if (tid < W1N + 256) {
    int m = tid - W1N;
    unsigned k0, k1; tf2x32(F0, F1, 0u, 1u, k0, k1);              // sk1
    unsigned o0, o1; tf2x32(k0, k1, 0u, (unsigned)m, o0, o1);
    b1s[m] = fmaf(rng_normal(o0 ^ o1), softplusf(b1_rho[m]), b1_mu[m]);
  } else if (tid < W1N + 512) {
    int m = tid - (W1N + 256);
    unsigned k0, k1; tf2x32(F0, F1, 0u, 2u, k0, k1);              // sk2
    unsigned o0, o1; tf2x32(k0, k1, 0u, (unsigned)m, o0, o1);
    w2s[m] = fmaf(rng_normal(o0 ^ o1), softplusf(w2_rho[m]), w2_mu[m]);
  } else if (tid == W1N + 512) {
    unsigned k0, k1; tf2x32(F0, F1, 0u, 3u, k0, k1);              // sk3
    unsigned o0, o1; tf2x32(k0, k1, 0u, 0u, o0, o1);
    b2s[0] = fmaf(rng_normal(o0 ^ o1), softplusf(b2_rho[0]), b2_mu[0]);
  }
}

// Pack A = [W1[:,256:522]; W1[:,778:1044]] -> As[512][288] bf16 (zero-padded K)
__global__ void pack_kernel(const float* __restrict__ W1s, __hip_bfloat16* __restrict__ As)
{
  int idx = blockIdx.x * blockDim.x + threadIdx.x;
  if (idx >= 512 * 288) return;
  int m = idx / 288, j = idx - m * 288;
  float v = 0.0f;
  if (j < 266) v = (m < 256) ? W1s[m*1044 + 256 + j] : W1s[(m-256)*1044 + 778 + j];
  As[idx] = __float2bfloat16(v);
}

// c[k] = b1s[k] + sum_j W1s[k][j] * q[j]   (q slice, cols 0..255)
__global__ void c_kernel(const float* __restrict__ W1s, const float* __restrict__ b1s,
                         const float* __restrict__ q, float* __restrict__ cvec)
{
  int k = threadIdx.x;
  float acc = b1s[k];
  for (int j = 0; j < 256; ++j) acc = fmaf(W1s[k*1044 + j], q[j], acc);
  cvec[k] = acc;
}

// Ar[r][k] = sum_j W1s[k][522+j] * rel[r][j]
__global__ void ar_kernel(const float* __restrict__ W1s, const float* __restrict__ rel,
                          float* __restrict__ Ar)
{
  __shared__ float rsh[256];
  int r = blockIdx.x, k = threadIdx.x;
  rsh[k] = rel[(size_t)r*256 + k];
  __syncthreads();
  float acc = 0.0f;
  for (int j = 0; j < 256; ++j) acc = fmaf(W1s[k*1044 + 522 + j], rsh[j], acc);
  Ar[(size_t)r*256 + k] = acc;
}

// ---------------------------------------------------------------------------
// MFMA GEMM: U[n][m] = sum_k He[n][k] * As[m][k]; bf16 in, bf16 out (f32 acc)
// block = 128 entities x 128 m ; wave = 32n x 128m (2x8 fragments)
// no LDS, no barriers: A/B fragments load straight from global (As L2-resident)
// ---------------------------------------------------------------------------
__global__ __launch_bounds__(256) void gemm_mfma(const __hip_bfloat16* __restrict__ He,
                                                 const __hip_bfloat16* __restrict__ As,
                                                 __hip_bfloat16* __restrict__ U, int nEnt)
{
  const int wid  = threadIdx.x >> 6;
  const int lane = threadIdx.x & 63;
  const int n0 = blockIdx.x * 128 + wid * 32;
  const int m0 = blockIdx.y * 128;
  const int lr = lane & 15;
  const int lk = (lane >> 4) * 8;

  f32x4 acc[2][8] = {};

  int na = n0 + lr, nb = n0 + 16 + lr;
  const short* pa = (const short*)He + (size_t)(na < nEnt ? na : 0) * 288 + lk;
  const short* pb = (const short*)He + (size_t)(nb < nEnt ? nb : 0) * 288 + lk;
  const short* pB = (const short*)As + (size_t)(m0 + lr) * 288 + lk;

  #pragma unroll
  for (int k0 = 0; k0 < 288; k0 += 32) {
    short8 a0 = *reinterpret_cast<const short8*>(pa + k0);
    short8 a1 = *reinterpret_cast<const short8*>(pb + k0);
    short8 b[8];
    #pragma unroll
    for (int j = 0; j < 8; ++j)
      b[j] = *reinterpret_cast<const short8*>(pB + (size_t)j * 16 * 288 + k0);
    #pragma unroll
    for (int j = 0; j < 8; ++j) {
      acc[0][j] = __builtin_amdgcn_mfma_f32_16x16x32_bf16(a0, b[j], acc[0][j], 0, 0, 0);
      acc[1][j] = __builtin_amdgcn_mfma_f32_16x16x32_bf16(a1, b[j], acc[1][j], 0, 0, 0);
    }
  }

  // D layout: col(m) = lane&15, row(n) = (lane>>4)*4 + r   [m89-verified]
  const int rowbase = (lane >> 4) * 4;
  #pragma unroll
  for (int nf = 0; nf < 2; ++nf) {
    #pragma unroll
    for (int r = 0; r < 4; ++r) {
      int n = n0 + nf * 16 + rowbase + r;
      if (n < nEnt) {
        #pragma unroll
        for (int j = 0; j < 8; ++j)
          U[(size_t)n * 512 + m0 + j * 16 + lr] = __float2bfloat16(acc[nf][j][r]);
      }
    }
  }
}

// ---------------------------------------------------------------------------
// Edge pass: 32 lanes per edge, 8 m-values per lane (bf16 U rows).
// pre[k] = c[k] + U[h][k] + Ar[r][k] + U[t][256+k];  out += w2 . relu(pre) + b2
// mode 0: store, 1: accumulate, 2: accumulate + *0.2
// ---------------------------------------------------------------------------
__global__ __launch_bounds__(256) void edge_kernel(const int* __restrict__ h,
                                                   const int* __restrict__ t,
                                                   const int* __restrict__ r,
                                                   const __hip_bfloat16* __restrict__ U,
                                                   const float* __restrict__ Ar,
                                                   const float* __restrict__ cvec,
                                                   const float* __restrict__ w2s,
                                                   const float* __restrict__ b2s,
                                                   float* __restrict__ out, int E, int mode)
{
  int e = blockIdx.x * 8 + (threadIdx.x >> 5);
  int l = threadIdx.x & 31;
  if (e >= E) return;
  int hh = h[e], tt = t[e], rr = r[e];
  const ushort* Ub = (const ushort*)U;

  uint4 uhv = *reinterpret_cast<const uint4*>(Ub + (size_t)hh * 512 + l * 8);
  uint4 utv = *reinterpret_cast<const uint4*>(Ub + (size_t)tt * 512 + 256 + l * 8);
  float4 ar0 = *reinterpret_cast<const float4*>(&Ar[(size_t)rr * 256 + l * 8]);
  float4 ar1 = *reinterpret_cast<const float4*>(&Ar[(size_t)rr * 256 + l * 8 + 4]);
  float4 c0  = *reinterpret_cast<const float4*>(&cvec[l * 8]);
  float4 c1  = *reinterpret_cast<const float4*>(&cvec[l * 8 + 4]);
  float4 w0  = *reinterpret_cast<const float4*>(&w2s[l * 8]);
  float4 w1  = *reinterpret_cast<const float4*>(&w2s[l * 8 + 4]);

  float uh[8], ut[8];
  uh[0] = __uint_as_float(uhv.x << 16); uh[1] = __uint_as_float(uhv.x & 0xFFFF0000u);
  uh[2] = __uint_as_float(uhv.y << 16); uh[3] = __uint_as_float(uhv.y & 0xFFFF0000u);
  uh[4] = __uint_as_float(uhv.z << 16); uh[5] = __uint_as_float(uhv.z & 0xFFFF0000u);
  uh[6] = __uint_as_float(uhv.w << 16); uh[7] = __uint_as_float(uhv.w & 0xFFFF0000u);
  ut[0] = __uint_as_float(utv.x << 16); ut[1] = __uint_as_float(utv.x & 0xFFFF0000u);
  ut[2] = __uint_as_float(utv.y << 16); ut[3] = __uint_as_float(utv.y & 0xFFFF0000u);
  ut[4] = __uint_as_float(utv.z << 16); ut[5] = __uint_as_float(utv.z & 0xFFFF0000u);
  ut[6] = __uint_as_float(utv.w << 16); ut[7] = __uint_as_float(utv.w & 0xFFFF0000u);

  const float cc[8] = {c0.x, c0.y, c0.z, c0.w, c1.x, c1.y, c1.z, c1.w};
  const float aa[8] = {ar0.x, ar0.y, ar0.z, ar0.w, ar1.x, ar1.y, ar1.z, ar1.w};
  const float ww[8] = {w0.x, w0.y, w0.z, w0.w, w1.x, w1.y, w1.z, w1.w};

  float sum = 0.0f;
  #pragma unroll
  for (int i = 0; i < 8; ++i)
    sum += ww[i] * fmaxf(cc[i] + uh[i] + aa[i] + ut[i], 0.0f);

  #pragma unroll
  for (int off = 16; off >= 1; off >>= 1) sum += __shfl_down(sum, off, 32);

  if (l == 0) {
    float v = sum + b2s[0];
    if (mode == 0)      out[e] = v;
    else if (mode == 1) out[e] += v;
    else                out[e] = (out[e] + v) * 0.2f;
  }
}

// ---------------------------------------------------------------------------
// Host launcher
// ---------------------------------------------------------------------------
extern "C" void kernel_launch(void* const* d_in, const int* in_sizes, int n_in,
                              void* d_out, int out_size, void* d_ws, size_t ws_size,
                              hipStream_t stream)
{
  const int*   h_id  = (const int*)  d_in[0];
  const int*   r_id  = (const int*)  d_in[1];
  const int*   t_id  = (const int*)  d_in[2];
  const float* q     = (const float*)d_in[3];
  const float* emb   = (const float*)d_in[4];
  const float* rel   = (const float*)d_in[6];
  const float* topic = (const float*)d_in[7];
  const float* nte   = (const float*)d_in[8];
  const float* w1_mu = (const float*)d_in[9];
  const float* w1_rho= (const float*)d_in[10];
  const float* b1_mu = (const float*)d_in[11];
  const float* b1_rho= (const float*)d_in[12];
  const float* w2_mu = (const float*)d_in[13];
  const float* w2_rho= (const float*)d_in[14];
  const float* b2_mu = (const float*)d_in[15];
  const float* b2_rho= (const float*)d_in[16];

  const int E     = in_sizes[0];
  const int nText = in_sizes[4] / 256;
  const int N     = in_sizes[7] / 2;
  const int NR    = in_sizes[6] / 256;
  float* out = (float*)d_out;

  char* ws = (char*)d_ws;
  size_t off = 0;
  auto alloc = [&](size_t bytes) -> void* {
    void* p = (void*)(ws + off);
    off += (bytes + 255) & ~(size_t)255;
    return p;
  };
  __hip_bfloat16* He  = (__hip_bfloat16*)alloc((size_t)N * 288 * 2);
  __hip_bfloat16* U   = (__hip_bfloat16*)alloc((size_t)N * 512 * 2);
  __hip_bfloat16* As  = (__hip_bfloat16*)alloc(512 * 288 * 2);
  float* W1s  = (float*)alloc(267264 * 4);
  float* b1s  = (float*)alloc(256 * 4);
  float* w2s  = (float*)alloc(256 * 4);
  float* b2s  = (float*)alloc(64 * 4);
  float* cvec = (float*)alloc(256 * 4);
  float* Ar   = (float*)alloc((size_t)NR * 256 * 4);
  float* cnt_t = (float*)alloc((size_t)N * 4);
  float* cnt_h = (float*)alloc((size_t)N * 4);
  float* f1 = (float*)alloc((size_t)2 * N * 4);
  float* f2 = (float*)alloc((size_t)2 * N * 4);
  float* g1 = (float*)alloc((size_t)2 * N * 4);
  float* g2 = (float*)alloc((size_t)2 * N * 4);

  // zero the atomic-accumulated DDE region (cnt_t .. g2, contiguous)
  size_t dde_bytes = (size_t)((char*)(g2 + 2*(size_t)N) - (char*)cnt_t);
  hipMemsetAsync(cnt_t, 0, dde_bytes, stream);

  int eb = (E + 255) / 256;
  int nb = (N + 255) / 256;
  dde_count   <<<eb, 256, 0, stream>>>(h_id, t_id, cnt_t, cnt_h, E);
  dde_scatter1<<<eb, 256, 0, stream>>>(h_id, t_id, topic, f1, g1, E);
  dde_norm    <<<nb, 256, 0, stream>>>(f1, g1, cnt_t, cnt_h, N);
  dde_scatter2<<<eb, 256, 0, stream>>>(h_id, t_id, f1, g1, f2, g2, E);
  dde_norm    <<<nb, 256, 0, stream>>>(f2, g2, cnt_t, cnt_h, N);

  int heb = ((int)((size_t)N * 288) + 255) / 256;
  build_he<<<heb, 256, 0, stream>>>(emb, nte, topic, f1, f2, g1, g2, He, N, nText);

  dim3 ggrid((N + 127) / 128, 4);
  for (int s = 0; s < 5; ++s) {
    sample_kernel<<<(267264 + 513 + 255) / 256, 256, 0, stream>>>(
        s, w1_mu, w1_rho, b1_mu, b1_rho, w2_mu, w2_rho, b2_mu, b2_rho,
        W1s, b1s, w2s, b2s);
    pack_kernel<<<(512*288 + 255)/256, 256, 0, stream>>>(W1s, As);
    c_kernel   <<<1, 256, 0, stream>>>(W1s, b1s, q, cvec);
    ar_kernel  <<<NR, 256, 0, stream>>>(W1s, rel, Ar);
    gemm_mfma  <<<ggrid, 256, 0, stream>>>(He, As, U, N);
    int mode = (s == 0) ? 0 : ((s == 4) ? 2 : 1);
    edge_kernel<<<(E + 7) / 8, 256, 0, stream>>>(h_id, t_id, r_id, U, Ar, cvec,
                                                 w2s, b2s, out, E, mode);
  }
  (void)n_in; (void)out_size; (void)ws_size;
}